// Round 7
// baseline (790.831 us; speedup 1.0000x reference)
//
#include <hip/hip_runtime.h>
#include <hip/hip_bf16.h>

using bf16 = __bf16;
typedef __bf16 bf16x8 __attribute__((ext_vector_type(8)));
typedef float  f32x4  __attribute__((ext_vector_type(4)));

#define MFMA16(a, b, c) __builtin_amdgcn_mfma_f32_16x16x32_bf16((a), (b), (c), 0, 0, 0)

// packed weight layout (bf16 element offsets in d_ws); fragment order:
// element j of lane L -> W[kt*32 + (L>>4)*8 + j][nt*16 + (L&15)], zero-padded.
constexpr int P0  = 0;
constexpr int P1  = 16384;
constexpr int P2  = 81920;
constexpr int P3  = 147456;
constexpr int P4  = 212992;
constexpr int P5  = 278528;
constexpr int P6  = 360448;
constexpr int P7  = 425984;
constexpr int PD  = 491520;
constexpr int PC0 = 495616;
constexpr int PC1 = 532480;

constexpr int NPTS = 4096 * 128;
constexpr int SA = 328;               // HA stride (656B = 41*16)
constexpr int SB = 296;               // HB stride (592B = 37*16)

// ------------------------------- pack kernel -------------------------------
// Weights arrive as float32 [K, N]; emit bf16 MFMA B-fragments.
struct PackArgs {
    const float* src[11];
    int K[11], N[11], Ntiles[11], tasks[11], dstoff[11];
};

__global__ void nerf_pack(PackArgs pa, bf16* __restrict__ dst) {
    int idx = blockIdx.x * 256 + threadIdx.x;
    for (int l = 0; l < 11; ++l) {
        if (idx < pa.tasks[l]) {
            const int lane = idx & 63;
            const int blk  = idx >> 6;
            const int nt   = blk % pa.Ntiles[l];
            const int kt   = blk / pa.Ntiles[l];
            const int kb   = kt * 32 + (lane >> 4) * 8;
            const int n    = nt * 16 + (lane & 15);
            const float* s = pa.src[l];
            const int K = pa.K[l], N = pa.N[l];
            bf16x8 v;
#pragma unroll
            for (int j = 0; j < 8; ++j) {
                int k = kb + j;
                v[j] = (bf16)((k < K && n < N) ? s[(size_t)k * N + n] : 0.f);
            }
            *(bf16x8*)(dst + pa.dstoff[l] + (size_t)idx * 8) = v;
            return;
        }
        idx -= pa.tasks[l];
    }
}

// ------------------------------- layer -------------------------------------
// C[64, N] = act(A[64, KP] @ Wpacked + bias).  bias is float32.
// MODE 0: bf16 -> LDS dst (stride dstride). MODE 1: density -> gout[m0+row] (f32).
// MODE 2: color -> gout[(m0+row)*3 + col] (f32), cols 0..2.
template <int KP, int N, bool RELU, int MODE>
__device__ __forceinline__ void layer(const bf16* src, int sstride,
                                      const bf16* __restrict__ wp,
                                      const float* __restrict__ bias,
                                      bf16* dst, int dstride,
                                      float* __restrict__ gout, int m0) {
    constexpr int NTILES = N / 16;
    constexpr int NT_W   = (NTILES < 4) ? NTILES : 4;  // n-tiles per wave
    constexpr int CG     = NTILES / NT_W;              // wave col-groups
    constexpr int MT_W   = 4 / (4 / CG);               // m-tiles per wave

    const int tid  = threadIdx.x;
    const int lane = tid & 63;
    const int w    = tid >> 6;
    const int l15  = lane & 15;
    const int quad = lane >> 4;
    const int mt0  = (w / CG) * MT_W;
    const int nt0  = (w % CG) * NT_W;

    f32x4 acc[MT_W][NT_W];
#pragma unroll
    for (int i = 0; i < MT_W; ++i)
#pragma unroll
        for (int j = 0; j < NT_W; ++j) {
            f32x4 z = {0.f, 0.f, 0.f, 0.f};
            acc[i][j] = z;
        }

#pragma unroll 2
    for (int kt = 0; kt < KP / 32; ++kt) {
        bf16x8 b[NT_W];
#pragma unroll
        for (int nt = 0; nt < NT_W; ++nt)
            b[nt] = *(const bf16x8*)(wp + ((size_t)(kt * NTILES + nt0 + nt) * 64 + lane) * 8);
#pragma unroll
        for (int mi = 0; mi < MT_W; ++mi) {
            const int row = (mt0 + mi) * 16 + l15;
            bf16x8 a = *(const bf16x8*)(src + row * sstride + kt * 32 + quad * 8);
#pragma unroll
            for (int nt = 0; nt < NT_W; ++nt)
                acc[mi][nt] = MFMA16(a, b[nt], acc[mi][nt]);
        }
    }
    __syncthreads();   // all reads done before any writes land

#pragma unroll
    for (int nt = 0; nt < NT_W; ++nt) {
        const int col = (nt0 + nt) * 16 + l15;
        float bv = 0.f;
        if (MODE == 0)      bv = bias[col];
        else if (MODE == 1) { if (l15 == 0) bv = bias[0]; }
        else                { if (l15 < 3)  bv = bias[l15]; }
#pragma unroll
        for (int mi = 0; mi < MT_W; ++mi) {
            const int rowb = (mt0 + mi) * 16 + quad * 4;
#pragma unroll
            for (int r = 0; r < 4; ++r) {
                float v = acc[mi][nt][r] + bv;
                if (RELU) v = v > 0.f ? v : 0.f;
                if (MODE == 0) {
                    dst[(rowb + r) * dstride + col] = (bf16)v;
                } else if (MODE == 1) {
                    if (l15 == 0) gout[m0 + rowb + r] = v;          // f32 store
                } else {
                    if (l15 < 3) gout[(size_t)(m0 + rowb + r) * 3 + l15] = v;  // f32
                }
            }
        }
    }
    __syncthreads();
}

// ------------------------------- main kernel -------------------------------
__global__ __launch_bounds__(256, 2)
void nerf_main(const float* __restrict__ pos, const float* __restrict__ dir,
               const float* __restrict__ b0, const float* __restrict__ b1,
               const float* __restrict__ b2, const float* __restrict__ b3,
               const float* __restrict__ b4, const float* __restrict__ b5,
               const float* __restrict__ b6, const float* __restrict__ b7,
               const float* __restrict__ bd, const float* __restrict__ bc0,
               const float* __restrict__ bc1,
               const bf16* __restrict__ wpk, float* __restrict__ out) {
    __shared__ __align__(16) bf16 HA[64 * SA];   // cols 0..255 h, 256..315 embed_pos
    __shared__ __align__(16) bf16 HB[64 * SB];   // cols 0..255 h, 256..279 embed_dir

    const int m0 = blockIdx.x * 64;

    // zero-init LDS (K-padding columns must be zero)
    for (int i = threadIdx.x; i < 64 * SA; i += 256) HA[i] = (bf16)0.f;
    for (int i = threadIdx.x; i < 64 * SB; i += 256) HB[i] = (bf16)0.f;
    __syncthreads();

    // positional encoding (f32) -> HA cols 256..319 (316..319 stay zero)
    {
        const int row = threadIdx.x >> 2;
        const int cg  = threadIdx.x & 3;
        const size_t pb = (size_t)(m0 + row) * 3;
        float xs[3] = { pos[pb], pos[pb + 1], pos[pb + 2] };
#pragma unroll
        for (int j = 0; j < 16; ++j) {
            const int col = cg * 16 + j;
            float v = 0.f;
            if (col < 60) {
                const int c = col / 20, rem = col % 20, s = rem / 10, i = rem % 10;
                const float arg = xs[c] * (float)(1 << i);
                v = s ? cosf(arg) : sinf(arg);
            }
            HA[row * SA + 256 + col] = (bf16)v;
        }
    }
    __syncthreads();

    // trunk (ping-pong, never in-place; embed_pos preserved in HA cols 256..315)
    layer<64,  256, true, 0>(HA + 256, SA, wpk + P0, b0, HA, SA, nullptr, m0);
    layer<256, 256, true, 0>(HA, SA, wpk + P1, b1, HB, SB, nullptr, m0);
    layer<256, 256, true, 0>(HB, SB, wpk + P2, b2, HA, SA, nullptr, m0);
    layer<256, 256, true, 0>(HA, SA, wpk + P3, b3, HB, SB, nullptr, m0);
    layer<256, 256, true, 0>(HB, SB, wpk + P4, b4, HA, SA, nullptr, m0);
    // skip concat implicit: HA rows = [h5 (0..255) | embed_pos (256..315) | 0]
    layer<320, 256, true, 0>(HA, SA, wpk + P5, b5, HB, SB, nullptr, m0);
    layer<256, 256, true, 0>(HB, SB, wpk + P6, b6, HA, SA, nullptr, m0);
    layer<256, 256, true, 0>(HA, SA, wpk + P7, b7, HB, SB, nullptr, m0); // h8 -> HB

    // density head (reads HB cols 0..255) -> f32 out[0 .. NPTS)
    layer<256, 16, false, 1>(HB, SB, wpk + PD, bd, nullptr, 0, out, m0);

    // dir encoding -> HB cols 256..287 (280..287 stay zero)
    {
        const int row = threadIdx.x >> 2;
        const int cg  = threadIdx.x & 3;
        const size_t db = (size_t)(m0 + row) * 3;
        float ds[3] = { dir[db], dir[db + 1], dir[db + 2] };
#pragma unroll
        for (int j = 0; j < 8; ++j) {
            const int col = cg * 8 + j;
            float v = 0.f;
            if (col < 24) {
                const int c = col / 8, rem = col % 8, s = rem / 4, i = rem % 4;
                const float arg = ds[c] * (float)(1 << i);
                v = s ? cosf(arg) : sinf(arg);
            }
            HB[row * SB + 256 + col] = (bf16)v;
        }
    }
    __syncthreads();

    // color head: c0 = relu([h8|embed_dir] @ Wc0 + bc0) -> HA cols 0..127
    layer<288, 128, true, 0>(HB, SB, wpk + PC0, bc0, HA, SA, nullptr, m0);
    // color = c0 @ Wc1 + bc1 -> f32 out[NPTS + pt*3 + c]
    layer<128, 16, false, 2>(HA, SA, wpk + PC1, bc1, nullptr, 0, out + NPTS, m0);
}

// Loud sentinel if harness I/O layout differs from expectation.
__global__ void nerf_sentinel(float* __restrict__ out, float val) {
    if (threadIdx.x == 0 && blockIdx.x == 0) out[0] = val;
}

// ------------------------------- launcher ----------------------------------
extern "C" void kernel_launch(void* const* d_in, const int* in_sizes, int n_in,
                              void* d_out, int out_size, void* d_ws, size_t ws_size,
                              hipStream_t stream) {
    static const int exp2[24] = {
        1572864, 1572864,
        15360, 256, 65536, 256, 65536, 256, 65536, 256,
        65536, 256, 80896, 256, 65536, 256, 65536, 256,
        256, 1, 35840, 128, 384, 3
    };
    int bad = -1;
    if (n_in != 24) bad = 99;
    else {
        for (int i = 0; i < 24; ++i)
            if (in_sizes[i] != exp2[i]) { bad = i; break; }
    }
    if (bad < 0 && out_size != NPTS * 4) bad = 97;
    if (bad >= 0) {
        nerf_sentinel<<<1, 64, 0, stream>>>((float*)d_out, 20000.f + 100.f * bad);
        return;
    }

    static const int wi[11] = {2, 4, 6, 8, 10, 12, 14, 16, 18, 20, 22};
    static const int Ks[11] = {60, 256, 256, 256, 256, 316, 256, 256, 256, 280, 128};
    static const int Ns[11] = {256, 256, 256, 256, 256, 256, 256, 256, 1, 128, 3};
    static const int Kp[11] = {64, 256, 256, 256, 256, 320, 256, 256, 256, 288, 128};
    static const int Np[11] = {256, 256, 256, 256, 256, 256, 256, 256, 16, 128, 16};

    PackArgs pa;
    int off = 0, total_tasks = 0;
    for (int l = 0; l < 11; ++l) {
        pa.src[l]    = (const float*)d_in[wi[l]];
        pa.K[l]      = Ks[l];
        pa.N[l]      = Ns[l];
        pa.Ntiles[l] = Np[l] / 16;
        pa.tasks[l]  = (Kp[l] / 32) * (Np[l] / 16) * 64;
        pa.dstoff[l] = off;
        off += pa.tasks[l] * 8;
        total_tasks += pa.tasks[l];
    }
    bf16* wpk = (bf16*)d_ws;

    nerf_pack<<<(total_tasks + 255) / 256, 256, 0, stream>>>(pa, wpk);

    nerf_main<<<NPTS / 64, 256, 0, stream>>>(
        (const float*)d_in[0], (const float*)d_in[1],
        (const float*)d_in[3], (const float*)d_in[5], (const float*)d_in[7],
        (const float*)d_in[9], (const float*)d_in[11], (const float*)d_in[13],
        (const float*)d_in[15], (const float*)d_in[17], (const float*)d_in[19],
        (const float*)d_in[21], (const float*)d_in[23],
        wpk, (float*)d_out);
}

// Round 8
// 604.369 us; speedup vs baseline: 1.3085x; 1.3085x over previous
//
#include <hip/hip_runtime.h>
#include <hip/hip_bf16.h>

using bf16 = __bf16;
typedef __bf16 bf16x8 __attribute__((ext_vector_type(8)));
typedef __bf16 bf16x4 __attribute__((ext_vector_type(4)));
typedef float  f32x4  __attribute__((ext_vector_type(4)));

#define MFMA16(a, b, c) __builtin_amdgcn_mfma_f32_16x16x32_bf16((a), (b), (c), 0, 0, 0)

// packed weight layout (bf16 element offsets in d_ws); fragment order:
// element j of lane L -> W[kt*32 + (L>>4)*8 + j][nt*16 + (L&15)], zero-padded.
// Used as the MFMA *A* operand (A[m=chan][k]); same bytes as the old B use.
constexpr int P0  = 0;
constexpr int P1  = 16384;
constexpr int P2  = 81920;
constexpr int P3  = 147456;
constexpr int P4  = 212992;
constexpr int P5  = 278528;
constexpr int P6  = 360448;
constexpr int P7  = 425984;
constexpr int PD  = 491520;
constexpr int PC0 = 495616;
constexpr int PC1 = 532480;

constexpr int NPTS = 4096 * 128;
constexpr int SH = 328;   // H stride: 656 B = 41*16 B; 164 dwords = 4 mod 32 banks

// ------------------------------- pack kernel -------------------------------
struct PackArgs {
    const float* src[11];
    int K[11], N[11], Ntiles[11], tasks[11], dstoff[11];
};

__global__ void nerf_pack(PackArgs pa, bf16* __restrict__ dst) {
    int idx = blockIdx.x * 256 + threadIdx.x;
    for (int l = 0; l < 11; ++l) {
        if (idx < pa.tasks[l]) {
            const int lane = idx & 63;
            const int blk  = idx >> 6;
            const int nt   = blk % pa.Ntiles[l];
            const int kt   = blk / pa.Ntiles[l];
            const int kb   = kt * 32 + (lane >> 4) * 8;
            const int n    = nt * 16 + (lane & 15);
            const float* s = pa.src[l];
            const int K = pa.K[l], N = pa.N[l];
            bf16x8 v;
#pragma unroll
            for (int j = 0; j < 8; ++j) {
                int k = kb + j;
                v[j] = (bf16)((k < K && n < N) ? s[(size_t)k * N + n] : 0.f);
            }
            *(bf16x8*)(dst + pa.dstoff[l] + (size_t)idx * 8) = v;
            return;
        }
        idx -= pa.tasks[l];
    }
}

// ------------------------------- layer -------------------------------------
// In-place: C[64, N] = act(H[64, KP] @ Wpacked + bias), operands swapped so
// D[m=chan][n=point]: per lane 4 contiguous chans -> one packed b64 LDS store.
// MODE 0: -> H (bf16). MODE 1: density -> gout[m0+p] (f32). MODE 2: color ->
// gout[(m0+p)*3+c] (f32). HAZARD: barrier between K-loop reads and LDS writes.
template <int KP, int N, bool RELU, int MODE, bool HAZARD>
__device__ __forceinline__ void layer(const bf16* src, bf16* H,
                                      const bf16* __restrict__ wp,
                                      const float* __restrict__ bias,
                                      float* __restrict__ gout, int m0) {
    constexpr int NTILES = N / 16;                 // chan tiles
    constexpr int NT_W   = (NTILES < 4) ? NTILES : 4;
    constexpr int CG     = NTILES / NT_W;          // chan wave-groups
    constexpr int PT_W   = CG;                     // point tiles per wave (4 waves, M=64)

    const int tid  = threadIdx.x;
    const int lane = tid & 63;
    const int w    = tid >> 6;
    const int l15  = lane & 15;
    const int quad = lane >> 4;
    const int nt0  = (w % CG) * NT_W;
    const int pt0  = (w / CG) * PT_W;

    // bias folded into acc init: acc element r <-> chan (nt0+nt)*16 + quad*4 + r
    f32x4 bias4[NT_W];
    if constexpr (MODE == 0) {
#pragma unroll
        for (int nt = 0; nt < NT_W; ++nt)
            bias4[nt] = *(const f32x4*)(bias + (nt0 + nt) * 16 + quad * 4);
    } else if constexpr (MODE == 1) {
        const float bv = bias[0];
        f32x4 t = {bv, bv, bv, bv}; bias4[0] = t;
    } else {
        f32x4 t = {bias[0], bias[1], bias[2], 0.f}; bias4[0] = t;
    }

    f32x4 acc[PT_W][NT_W];
#pragma unroll
    for (int pt = 0; pt < PT_W; ++pt)
#pragma unroll
        for (int nt = 0; nt < NT_W; ++nt) acc[pt][nt] = bias4[nt];

#pragma unroll 2
    for (int kt = 0; kt < KP / 32; ++kt) {
        bf16x8 wf[NT_W];
#pragma unroll
        for (int nt = 0; nt < NT_W; ++nt)
            wf[nt] = *(const bf16x8*)(wp + ((size_t)(kt * NTILES + nt0 + nt) * 64 + lane) * 8);
#pragma unroll
        for (int pt = 0; pt < PT_W; ++pt) {
            const int point = (pt0 + pt) * 16 + l15;
            bf16x8 af = *(const bf16x8*)(src + point * SH + kt * 32 + quad * 8);
#pragma unroll
            for (int nt = 0; nt < NT_W; ++nt)
                acc[pt][nt] = MFMA16(wf[nt], af, acc[pt][nt]);
        }
    }
    if (HAZARD) __syncthreads();   // all in-place reads done before writes

    if constexpr (MODE == 0) {
#pragma unroll
        for (int pt = 0; pt < PT_W; ++pt) {
            const int point = (pt0 + pt) * 16 + l15;
#pragma unroll
            for (int nt = 0; nt < NT_W; ++nt) {
                f32x4 a = acc[pt][nt];
                bf16x4 o;
#pragma unroll
                for (int r = 0; r < 4; ++r) {
                    float v = a[r];
                    if (RELU) v = v > 0.f ? v : 0.f;
                    o[r] = (bf16)v;
                }
                *(bf16x4*)(H + point * SH + (nt0 + nt) * 16 + quad * 4) = o;
            }
        }
        __syncthreads();           // writes visible before next layer reads
    } else if constexpr (MODE == 1) {
        if (quad == 0) gout[m0 + pt0 * 16 + l15] = acc[0][0][0];
    } else {
        if (quad == 0) {
            const size_t p3 = (size_t)(m0 + pt0 * 16 + l15) * 3;
            gout[p3 + 0] = acc[0][0][0];
            gout[p3 + 1] = acc[0][0][1];
            gout[p3 + 2] = acc[0][0][2];
        }
    }
}

// ------------------------------- main kernel -------------------------------
__global__ __launch_bounds__(256, 3)
void nerf_main(const float* __restrict__ pos, const float* __restrict__ dir,
               const float* __restrict__ b0, const float* __restrict__ b1,
               const float* __restrict__ b2, const float* __restrict__ b3,
               const float* __restrict__ b4, const float* __restrict__ b5,
               const float* __restrict__ b6, const float* __restrict__ b7,
               const float* __restrict__ bd, const float* __restrict__ bc0,
               const float* __restrict__ bc1,
               const bf16* __restrict__ wpk, float* __restrict__ out) {
    __shared__ __align__(16) bf16 H[64 * SH];   // 41984 B -> 3 blocks/CU

    const int m0 = blockIdx.x * 64;

    // zero only the K-pad cols 316..319 (weight pad rows are 0; pads just
    // must not be NaN). One store per thread.
    H[(threadIdx.x & 63) * SH + 316 + (threadIdx.x >> 6)] = (bf16)0.f;

    // positional encoding -> H cols 256..315 (15 cols per thread)
    {
        const int row = threadIdx.x >> 2;
        const int cg  = threadIdx.x & 3;
        const size_t pb = (size_t)(m0 + row) * 3;
        float xs[3] = { pos[pb], pos[pb + 1], pos[pb + 2] };
#pragma unroll
        for (int j = 0; j < 15; ++j) {
            const int col = cg * 15 + j;
            const int c = col / 20, rem = col % 20, s = rem / 10, i = rem % 10;
            const float arg = xs[c] * (float)(1 << i);
            float v = s ? __cosf(arg) : __sinf(arg);
            H[row * SH + 256 + col] = (bf16)v;
        }
    }
    __syncthreads();

    // trunk, in-place; embed_pos lives in cols 256..315 until L5 consumes it
    layer<64,  256, true, 0, false>(H + 256, H, wpk + P0, b0, nullptr, m0);
    layer<256, 256, true, 0, true >(H, H, wpk + P1, b1, nullptr, m0);
    layer<256, 256, true, 0, true >(H, H, wpk + P2, b2, nullptr, m0);
    layer<256, 256, true, 0, true >(H, H, wpk + P3, b3, nullptr, m0);
    layer<256, 256, true, 0, true >(H, H, wpk + P4, b4, nullptr, m0);
    layer<320, 256, true, 0, true >(H, H, wpk + P5, b5, nullptr, m0);  // skip concat
    layer<256, 256, true, 0, true >(H, H, wpk + P6, b6, nullptr, m0);
    layer<256, 256, true, 0, true >(H, H, wpk + P7, b7, nullptr, m0);  // h8 in cols 0..255

    // density head: reads cols 0..255, writes global only (no barrier needed)
    layer<256, 16, false, 1, false>(H, H, wpk + PD, bd, out, m0);

    // dir encoding -> cols 256..279, zero 280..287 (c0 K-pad); disjoint from
    // density's reads, so no barrier before; barrier after for c0.
    {
        const int row = threadIdx.x >> 2;
        const int cg  = threadIdx.x & 3;
        const size_t db = (size_t)(m0 + row) * 3;
        float ds[3] = { dir[db], dir[db + 1], dir[db + 2] };
#pragma unroll
        for (int j = 0; j < 8; ++j) {
            const int col = cg * 8 + j;
            float v = 0.f;
            if (col < 24) {
                const int c = col / 8, rem = col % 8, s = rem / 4, i = rem % 4;
                const float arg = ds[c] * (float)(1 << i);
                v = s ? __cosf(arg) : __sinf(arg);
            }
            H[row * SH + 256 + col] = (bf16)v;
        }
    }
    __syncthreads();

    // color head
    layer<288, 128, true, 0, true >(H, H, wpk + PC0, bc0, nullptr, m0); // c0 -> cols 0..127
    layer<128, 16, false, 2, false>(H, H, wpk + PC1, bc1, out + NPTS, m0);
}

// Loud sentinel if harness I/O layout differs from expectation.
__global__ void nerf_sentinel(float* __restrict__ out, float val) {
    if (threadIdx.x == 0 && blockIdx.x == 0) out[0] = val;
}

// ------------------------------- launcher ----------------------------------
extern "C" void kernel_launch(void* const* d_in, const int* in_sizes, int n_in,
                              void* d_out, int out_size, void* d_ws, size_t ws_size,
                              hipStream_t stream) {
    static const int exp2[24] = {
        1572864, 1572864,
        15360, 256, 65536, 256, 65536, 256, 65536, 256,
        65536, 256, 80896, 256, 65536, 256, 65536, 256,
        256, 1, 35840, 128, 384, 3
    };
    int bad = -1;
    if (n_in != 24) bad = 99;
    else {
        for (int i = 0; i < 24; ++i)
            if (in_sizes[i] != exp2[i]) { bad = i; break; }
    }
    if (bad < 0 && out_size != NPTS * 4) bad = 97;
    if (bad >= 0) {
        nerf_sentinel<<<1, 64, 0, stream>>>((float*)d_out, 20000.f + 100.f * bad);
        return;
    }

    static const int wi[11] = {2, 4, 6, 8, 10, 12, 14, 16, 18, 20, 22};
    static const int Ks[11] = {60, 256, 256, 256, 256, 316, 256, 256, 256, 280, 128};
    static const int Ns[11] = {256, 256, 256, 256, 256, 256, 256, 256, 1, 128, 3};
    static const int Kp[11] = {64, 256, 256, 256, 256, 320, 256, 256, 256, 288, 128};
    static const int Np[11] = {256, 256, 256, 256, 256, 256, 256, 256, 16, 128, 16};

    PackArgs pa;
    int off = 0, total_tasks = 0;
    for (int l = 0; l < 11; ++l) {
        pa.src[l]    = (const float*)d_in[wi[l]];
        pa.K[l]      = Ks[l];
        pa.N[l]      = Ns[l];
        pa.Ntiles[l] = Np[l] / 16;
        pa.tasks[l]  = (Kp[l] / 32) * (Np[l] / 16) * 64;
        pa.dstoff[l] = off;
        off += pa.tasks[l] * 8;
        total_tasks += pa.tasks[l];
    }
    bf16* wpk = (bf16*)d_ws;

    nerf_pack<<<(total_tasks + 255) / 256, 256, 0, stream>>>(pa, wpk);

    nerf_main<<<NPTS / 64, 256, 0, stream>>>(
        (const float*)d_in[0], (const float*)d_in[1],
        (const float*)d_in[3], (const float*)d_in[5], (const float*)d_in[7],
        (const float*)d_in[9], (const float*)d_in[11], (const float*)d_in[13],
        (const float*)d_in[15], (const float*)d_in[17], (const float*)d_in[19],
        (const float*)d_in[21], (const float*)d_in[23],
        wpk, (float*)d_out);
}